// Round 2
// baseline (983.265 us; speedup 1.0000x reference)
//
#include <hip/hip_runtime.h>

typedef unsigned short u16;
typedef unsigned int u32;
typedef short bf16x8 __attribute__((ext_vector_type(8)));
typedef float f32x4 __attribute__((ext_vector_type(4)));

// ---- bf16 helpers ----
__device__ __forceinline__ u16 f2bf(float f) {
  union { float f; u32 i; } v; v.f = f;
  u32 x = v.i;
  return (u16)((x + 0x7fffu + ((x >> 16) & 1u)) >> 16);  // RNE
}

union Pack16 { u16 h[16]; float4 f4[2]; };
struct Raw2 { float4 r[2]; };
struct Raw4 { float4 r[4]; };

// =====================================================================
// f32 -> bf16 streaming converters (memory-bound, ~8 us per 33.5 MB)
// =====================================================================
__global__ __launch_bounds__(256) void conv_a_kernel(const float* __restrict__ src,
                                                     u16* __restrict__ dst) {
  const size_t i = (size_t)blockIdx.x * 256 + threadIdx.x;  // 1,048,576 threads, 8 elems each
  const float4* s = (const float4*)src + i * 2;
  float4 a = s[0], b = s[1];
  union { u16 h[8]; float4 f; } o;
  o.h[0] = f2bf(a.x); o.h[1] = f2bf(a.y); o.h[2] = f2bf(a.z); o.h[3] = f2bf(a.w);
  o.h[4] = f2bf(b.x); o.h[5] = f2bf(b.y); o.h[6] = f2bf(b.z); o.h[7] = f2bf(b.w);
  *(float4*)(dst + i * 8) = o.f;
}

struct W5 { const float* p[5]; };
__global__ __launch_bounds__(256) void conv_w_kernel(W5 w, u16* __restrict__ dst) {
  const int m = blockIdx.x >> 9;                       // matrix 0..4
  const size_t i = (size_t)(blockIdx.x & 511) * 256 + threadIdx.x;  // 0..131071 (x8 elems)
  const float4* s = (const float4*)w.p[m] + i * 2;
  float4 a = s[0], b = s[1];
  union { u16 h[8]; float4 f; } o;
  o.h[0] = f2bf(a.x); o.h[1] = f2bf(a.y); o.h[2] = f2bf(a.z); o.h[3] = f2bf(a.w);
  o.h[4] = f2bf(b.x); o.h[5] = f2bf(b.y); o.h[6] = f2bf(b.z); o.h[7] = f2bf(b.w);
  *(float4*)(dst + ((size_t)m << 20) + i * 8) = o.f;
}

// ---- A-operand raw load: A is ALWAYS bf16 now ----
// ASRC 0: bf16 row-major [8192][1024], row m.
// ASRC 1: bf16 Q-layout [N,H,S,DK]; m = n*1024+s; 16-run stays in one h.
template<int ASRC>
__device__ __forceinline__ void loadA(const void* __restrict__ A, int m, int k, Raw2& ra) {
  const u16* b;
  if constexpr (ASRC == 0) {
    b = (const u16*)A + (size_t)m * 1024 + k;
  } else {
    const int n = m >> 10, s = m & 1023, h = k >> 6;
    b = (const u16*)A + ((size_t)((n * 16 + h) * 1024 + s)) * 64 + (k & 63);
  }
  ra.r[0] = *(const float4*)b;
  ra.r[1] = *(const float4*)(b + 8);
}

// ---- W raw load: WBF=1 bf16 (2x float4), WBF=0 f32 fallback (4x float4) ----
template<int WBF>
__device__ __forceinline__ void loadW(const void* __restrict__ W, int col, int k, Raw4& rw) {
  if constexpr (WBF) {
    const u16* b = (const u16*)W + (size_t)col * 1024 + k;
    rw.r[0] = *(const float4*)b;
    rw.r[1] = *(const float4*)(b + 8);
  } else {
    const float4* f = (const float4*)((const float*)W + (size_t)col * 1024 + k);
    rw.r[0] = f[0]; rw.r[1] = f[1]; rw.r[2] = f[2]; rw.r[3] = f[3];
  }
}

// =====================================================================
// GEMM: C[m][col] = sum_k A[m][k] * W[col][k] + bias[col]
// MODE 0 (proj):  out -> bf16 Q-layout [N,H,S,DK]
// MODE 1 (fc):    out -> f32 [S,N,D]
// MODE 2 (Vproj): out -> bf16 TRANSPOSED head layout [N,H,DK,S]  (V^T)
// 128x128 block tile, BK=32, 4 waves each 64x64 (4x4 MFMA tiles).
// Ping-pong register prefetch (static buffer names, no runtime index).
// =====================================================================
template<int MODE, int ASRC, int WBF>
__global__ __launch_bounds__(256, 2) void gemm_bt(const void* __restrict__ A,
                                                  const void* __restrict__ W,
                                                  const float* __restrict__ bias,
                                                  void* __restrict__ outv) {
  __shared__ __align__(16) u16 At[128 * 40];  // stride 40 u16: rows 80B, 2-way banks (free)
  __shared__ __align__(16) u16 Bt[128 * 40];

  const int tid = threadIdx.x;
  const int lane = tid & 63, wave = tid >> 6;
  const int quad = lane >> 4, l16 = lane & 15;
  const int bm = blockIdx.y * 128, bn = blockIdx.x * 128;
  const int wm = (wave >> 1) * 64, wn = (wave & 1) * 64;
  const int srow = tid >> 1;            // 0..127
  const int scol = (tid & 1) * 16;      // 0 or 16

  f32x4 acc[4][4];
#pragma unroll
  for (int i = 0; i < 4; i++)
#pragma unroll
    for (int j = 0; j < 4; j++) acc[i][j] = (f32x4){0.f, 0.f, 0.f, 0.f};

  u16* sA = At + srow * 40 + scol;
  u16* sB = Bt + srow * 40 + scol;

  Raw2 a0, a1; Raw4 w0, w1;
  loadA<ASRC>(A, bm + srow, scol, a0);
  loadW<WBF>(W, bn + srow, scol, w0);

  auto kstep = [&](Raw2& aC, Raw4& wC, Raw2& aN, Raw4& wN, int k, bool pf) {
    if (pf) {  // issue next-step loads before waiting on current
      loadA<ASRC>(A, bm + srow, k + 32, aN);
      loadW<WBF>(W, bn + srow, k + 32, wN);
    }
    Pack16 pb;
    if constexpr (!WBF) {
#pragma unroll
      for (int q = 0; q < 4; q++) {
        pb.h[q * 4 + 0] = f2bf(wC.r[q].x);
        pb.h[q * 4 + 1] = f2bf(wC.r[q].y);
        pb.h[q * 4 + 2] = f2bf(wC.r[q].z);
        pb.h[q * 4 + 3] = f2bf(wC.r[q].w);
      }
    }
    __syncthreads();
    *(float4*)(sA) = aC.r[0]; *(float4*)(sA + 8) = aC.r[1];
    if constexpr (WBF) {
      *(float4*)(sB) = wC.r[0]; *(float4*)(sB + 8) = wC.r[1];
    } else {
      *(float4*)(sB) = pb.f4[0]; *(float4*)(sB + 8) = pb.f4[1];
    }
    __syncthreads();

    bf16x8 af[4], bfr[4];
#pragma unroll
    for (int mt = 0; mt < 4; mt++)
      af[mt] = *(const bf16x8*)(At + (wm + mt * 16 + l16) * 40 + quad * 8);
#pragma unroll
    for (int nt = 0; nt < 4; nt++)
      bfr[nt] = *(const bf16x8*)(Bt + (wn + nt * 16 + l16) * 40 + quad * 8);
#pragma unroll
    for (int mt = 0; mt < 4; mt++)
#pragma unroll
      for (int nt = 0; nt < 4; nt++)
        acc[mt][nt] = __builtin_amdgcn_mfma_f32_16x16x32_bf16(af[mt], bfr[nt], acc[mt][nt], 0, 0, 0);
  };

  for (int k0 = 0; k0 < 1024; k0 += 64) {
    kstep(a0, w0, a1, w1, scol + k0, true);
    kstep(a1, w1, a0, w0, scol + k0 + 32, k0 + 64 < 1024);
  }

#pragma unroll
  for (int mt = 0; mt < 4; mt++) {
#pragma unroll
    for (int nt = 0; nt < 4; nt++) {
      const int col = bn + wn + nt * 16 + l16;
      const float bv = bias[col];
#pragma unroll
      for (int i = 0; i < 4; i++) {
        const int row = bm + wm + mt * 16 + quad * 4 + i;
        const float v = acc[mt][nt][i] + bv;
        if constexpr (MODE == 0) {
          const int s = row >> 3, n = row & 7;
          const int h = col >> 6, dk = col & 63;
          ((u16*)outv)[(size_t)(((n * 16 + h) * 1024 + s) * 64 + dk)] = f2bf(v);
        } else if constexpr (MODE == 1) {
          const int n = row >> 10, s = row & 1023;
          ((float*)outv)[(size_t)((s * 8 + n) * 1024 + col)] = v;  // f32 output!
        } else {  // MODE 2: V^T head layout [N,H,DK,S]
          const int s = row >> 3, n = row & 7;
          const int h = col >> 6, dk = col & 63;
          ((u16*)outv)[(size_t)(((n * 16 + h) * 64 + dk) * 1024 + s)] = f2bf(v);
        }
      }
    }
  }
}

// =====================================================================
// Flash attention, IN-PLACE ctx into QC. V comes TRANSPOSED ([N,H,DK,S]).
// Vt LDS: no-pad [dk][key] with 8-key-block XOR swizzle -> both the
// float4 staging writes and the b128 PV reads are bank-uniform.
// Block: 256 thr = 4 waves, 64 queries (16/wave), key tiles of 64.
// grid: (16 qtiles, 128 nh)
// =====================================================================
__global__ __launch_bounds__(256, 2) void attn_kernel(u16* __restrict__ QC,
                                                      const u16* __restrict__ K,
                                                      const u16* __restrict__ Vt_g,
                                                      const int* __restrict__ mask) {
  __shared__ __align__(16) u16 Ks[64 * 72];     // [key][dk], stride 72
  __shared__ __align__(16) u16 Vt[64 * 64];     // [dk][key], XOR-swizzled 8-key blocks
  __shared__ __align__(16) u16 Ps[4 * 16 * 72]; // per-wave P tile [16][72]
  __shared__ float mbias[64];

  const int tid = threadIdx.x;
  const int lane = tid & 63, wave = tid >> 6;
  const int quad = lane >> 4, l16 = lane & 15;
  const int qt = blockIdx.x, nh = blockIdx.y;
  const int n = nh >> 4;
  const size_t base = (size_t)nh << 16;  // nh * 1024*64  (same size for K and V^T slabs)

  // Q fragments (A-operand layout), held in regs all kernel
  const int q0 = qt * 64 + wave * 16;
  bf16x8 qf0, qf1;
  {
    const u16* qp = QC + base + (size_t)(q0 + l16) * 64 + quad * 8;
    qf0 = *(const bf16x8*)qp;
    qf1 = *(const bf16x8*)(qp + 32);
  }

  float m_i[4], l_i[4];
  f32x4 o[4];
#pragma unroll
  for (int i = 0; i < 4; i++) { m_i[i] = -1e30f; l_i[i] = 0.f; }
#pragma unroll
  for (int d = 0; d < 4; d++) o[d] = (f32x4){0.f, 0.f, 0.f, 0.f};

  const int sr = tid >> 2;           // K: key row 0..63 | V^T: dk row 0..63
  const int sc = (tid & 3) * 16;     // K: dk offset     | V^T: key offset
  const u16* kbase = K + base + (size_t)sr * 64 + sc;
  const u16* vbase = Vt_g + base + (size_t)sr * 1024 + sc;  // V^T: [dk][1024 keys]
  // swizzled LDS dst for the two 8-key blocks this thread stages
  u16* vdst0 = Vt + sr * 64 + ((((sc >> 3) + 0) ^ (sr & 7)) << 3);
  u16* vdst1 = Vt + sr * 64 + ((((sc >> 3) + 1) ^ (sr & 7)) << 3);
  u16* pw = Ps + wave * (16 * 72);

  for (int kt = 0; kt < 16; kt++) {
    // ---- stage K tile (row-major) + V^T tile (swizzled) + mask bias ----
    float4 kv0 = *(const float4*)(kbase + kt * 64 * 64);
    float4 kv1 = *(const float4*)(kbase + kt * 64 * 64 + 8);
    float4 vv0 = *(const float4*)(vbase + kt * 64);
    float4 vv1 = *(const float4*)(vbase + kt * 64 + 8);
    int mk = (tid < 64) ? mask[n * 1024 + kt * 64 + tid] : 0;
    __syncthreads();  // protect previous iteration's LDS reads
    *(float4*)(Ks + sr * 72 + sc) = kv0;
    *(float4*)(Ks + sr * 72 + sc + 8) = kv1;
    *(float4*)vdst0 = vv0;
    *(float4*)vdst1 = vv1;
    if (tid < 64) mbias[tid] = mk ? -1e30f : 0.0f;
    __syncthreads();

    // ---- S = Q K^T / 8 + mask ----
    f32x4 sfr[4];
#pragma unroll
    for (int nt = 0; nt < 4; nt++) {
      bf16x8 b0 = *(const bf16x8*)(Ks + (nt * 16 + l16) * 72 + quad * 8);
      bf16x8 b1 = *(const bf16x8*)(Ks + (nt * 16 + l16) * 72 + 32 + quad * 8);
      f32x4 a = (f32x4){0.f, 0.f, 0.f, 0.f};
      a = __builtin_amdgcn_mfma_f32_16x16x32_bf16(qf0, b0, a, 0, 0, 0);
      a = __builtin_amdgcn_mfma_f32_16x16x32_bf16(qf1, b1, a, 0, 0, 0);
      sfr[nt] = a;
    }
    float mb[4];
#pragma unroll
    for (int nt = 0; nt < 4; nt++) mb[nt] = mbias[nt * 16 + l16];
#pragma unroll
    for (int nt = 0; nt < 4; nt++)
#pragma unroll
      for (int i = 0; i < 4; i++)
        sfr[nt][i] = sfr[nt][i] * 0.125f + mb[nt];

    // ---- online softmax: row = quad*4+i lives in this 16-lane group ----
    float alpha[4];
#pragma unroll
    for (int i = 0; i < 4; i++) {
      float m = fmaxf(fmaxf(sfr[0][i], sfr[1][i]), fmaxf(sfr[2][i], sfr[3][i]));
#pragma unroll
      for (int off = 1; off < 16; off <<= 1) m = fmaxf(m, __shfl_xor(m, off, 64));
      float mn = fmaxf(m_i[i], m);
      alpha[i] = __expf(m_i[i] - mn);
      m_i[i] = mn;
    }
    float rs[4] = {0.f, 0.f, 0.f, 0.f};
#pragma unroll
    for (int nt = 0; nt < 4; nt++) {
#pragma unroll
      for (int i = 0; i < 4; i++) {
        float p = __expf(sfr[nt][i] - m_i[i]);
        rs[i] += p;
        pw[(quad * 4 + i) * 72 + nt * 16 + l16] = f2bf(p);
      }
    }
#pragma unroll
    for (int i = 0; i < 4; i++) {
      float s = rs[i];
#pragma unroll
      for (int off = 1; off < 16; off <<= 1) s += __shfl_xor(s, off, 64);
      l_i[i] = l_i[i] * alpha[i] + s;
    }
#pragma unroll
    for (int d = 0; d < 4; d++)
#pragma unroll
      for (int i = 0; i < 4; i++) o[d][i] *= alpha[i];
    __syncthreads();  // P tile visible (also orders vs next staging)

    // ---- O += P @ V : B-fragment is ONE swizzled ds_read_b128 now ----
#pragma unroll
    for (int ks = 0; ks < 2; ks++) {
      bf16x8 pa = *(const bf16x8*)(pw + l16 * 72 + ks * 32 + quad * 8);
#pragma unroll
      for (int d = 0; d < 4; d++) {
        bf16x8 vb = *(const bf16x8*)(Vt + (d * 16 + l16) * 64 +
                                     (((ks * 4 + quad) ^ (l16 & 7)) << 3));
        o[d] = __builtin_amdgcn_mfma_f32_16x16x32_bf16(pa, vb, o[d], 0, 0, 0);
      }
    }
  }

  // ---- epilogue: write ctx IN-PLACE into the block's own Q slab ----
#pragma unroll
  for (int i = 0; i < 4; i++) {
    const float inv = 1.0f / l_i[i];
    const int q = q0 + quad * 4 + i;
    const size_t ob = base + (size_t)q * 64;
#pragma unroll
    for (int d = 0; d < 4; d++)
      QC[ob + d * 16 + l16] = f2bf(o[d][i] * inv);
  }
}

// =====================================================================
extern "C" void kernel_launch(void* const* d_in, const int* in_sizes, int n_in,
                              void* d_out, int out_size, void* d_ws, size_t ws_size,
                              hipStream_t stream) {
  const float* Qpoi = (const float*)d_in[0];
  const float* Qsvi = (const float*)d_in[1];
  const float* Kin  = (const float*)d_in[2];
  const float* Vin  = (const float*)d_in[3];
  const int* mask   = (const int*)d_in[4];
  const float* wq_poi_w = (const float*)d_in[5];
  const float* wq_poi_b = (const float*)d_in[6];
  const float* wq_svi_w = (const float*)d_in[7];
  const float* wq_svi_b = (const float*)d_in[8];
  const float* wk_w = (const float*)d_in[9];
  const float* wk_b = (const float*)d_in[10];
  const float* wv_w = (const float*)d_in[11];
  const float* wv_b = (const float*)d_in[12];
  const float* fc_w = (const float*)d_in[13];
  const float* fc_b = (const float*)d_in[14];

  const size_t SZ = (size_t)8 * 16 * 1024 * 64;  // 8,388,608 elems per slab
  u16* W0 = (u16*)d_ws;        // Kh head-layout; later poi-ctx bounce
  u16* W1 = W0 + SZ;           // Vh TRANSPOSED head-layout [N,H,DK,S]
  u16* Wb = W1 + SZ;           // bf16 weights (5 x 1M elems) if ws fits
  const bool wbf = ws_size >= (2 * SZ + 5 * ((size_t)1 << 20)) * sizeof(u16);
  float* Of = (float*)d_out;   // f32 [2][SZ]
  u16* Qs = (u16*)d_out;       // bf16 scratch: d_out bytes [0, 16.78 MB)
  u16* Ab = Qs + SZ;           // bf16 A-conv scratch: d_out bytes [16.78, 33.5 MB)

  dim3 bb(256, 1, 1);
  dim3 gg(8, 64);     // gemm: 512 blocks
  dim3 ga(16, 128);   // attn
  dim3 gc(4096);      // conv_a
  dim3 gw(2560);      // conv_w (5 x 512)

  if (wbf) {
    W5 w5{{wk_w, wv_w, wq_svi_w, wq_poi_w, fc_w}};
    hipLaunchKernelGGL(conv_w_kernel, gw, bb, 0, stream, w5, Wb);
  }
  const void* Wk  = wbf ? (const void*)(Wb + ((size_t)0 << 20)) : (const void*)wk_w;
  const void* Wv  = wbf ? (const void*)(Wb + ((size_t)1 << 20)) : (const void*)wv_w;
  const void* Wqs = wbf ? (const void*)(Wb + ((size_t)2 << 20)) : (const void*)wq_svi_w;
  const void* Wqp = wbf ? (const void*)(Wb + ((size_t)3 << 20)) : (const void*)wq_poi_w;
  const void* Wfc = wbf ? (const void*)(Wb + ((size_t)4 << 20)) : (const void*)fc_w;

#define GEMM(M, WS, a, w, b, o)                                                        \
  do {                                                                                 \
    if (wbf) hipLaunchKernelGGL((gemm_bt<M, WS, 1>), gg, bb, 0, stream, a, w, b, o);   \
    else     hipLaunchKernelGGL((gemm_bt<M, WS, 0>), gg, bb, 0, stream, a, w, b, o);   \
  } while (0)

  // shared K/V projections -> ws (K head-layout, V transposed head-layout)
  hipLaunchKernelGGL(conv_a_kernel, gc, bb, 0, stream, Kin, Ab);
  GEMM(0, 0, (const void*)Ab, Wk, wk_b, (void*)W0);
  hipLaunchKernelGGL(conv_a_kernel, gc, bb, 0, stream, Vin, Ab);
  GEMM(2, 0, (const void*)Ab, Wv, wv_b, (void*)W1);

  // ---- svi path ----
  hipLaunchKernelGGL(conv_a_kernel, gc, bb, 0, stream, Qsvi, Ab);
  GEMM(0, 0, (const void*)Ab, Wqs, wq_svi_b, (void*)Qs);
  hipLaunchKernelGGL(attn_kernel, ga, bb, 0, stream, Qs, W0, W1, mask);   // ctx in-place
  GEMM(1, 1, (const void*)Qs, Wfc, fc_b, (void*)(Of + SZ));

  // ---- poi path ----
  hipLaunchKernelGGL(conv_a_kernel, gc, bb, 0, stream, Qpoi, Ab);
  GEMM(0, 0, (const void*)Ab, Wqp, wq_poi_b, (void*)Qs);
  hipLaunchKernelGGL(attn_kernel, ga, bb, 0, stream, Qs, W0, W1, mask);   // ctx in-place
  hipMemcpyAsync(W0, Qs, SZ * sizeof(u16), hipMemcpyDeviceToDevice, stream);
  GEMM(1, 1, (const void*)W0, Wfc, fc_b, (void*)Of);
#undef GEMM
}

// Round 3
// 612.206 us; speedup vs baseline: 1.6061x; 1.6061x over previous
//
#include <hip/hip_runtime.h>

typedef unsigned short u16;
typedef unsigned int u32;
typedef short bf16x8 __attribute__((ext_vector_type(8)));
typedef float f32x4 __attribute__((ext_vector_type(4)));

// ---- bf16 helpers ----
__device__ __forceinline__ u16 f2bf(float f) {
  union { float f; u32 i; } v; v.f = f;
  u32 x = v.i;
  return (u16)((x + 0x7fffu + ((x >> 16) & 1u)) >> 16);  // RNE
}

union Pack16 { u16 h[16]; float4 f4[2]; };

// ---- direct global->LDS DMA, 16B per lane (wave-uniform LDS base) ----
__device__ __forceinline__ void gld16(const u16* g, u16* l) {
  __builtin_amdgcn_global_load_lds((const __attribute__((address_space(1))) u32*)g,
                                   (__attribute__((address_space(3))) u32*)l, 16, 0, 0);
}

// =====================================================================
// f32 -> bf16 streaming converters
// =====================================================================
__global__ __launch_bounds__(256) void conv_a_kernel(const float* __restrict__ src,
                                                     u16* __restrict__ dst) {
  const size_t i = (size_t)blockIdx.x * 256 + threadIdx.x;  // 1,048,576 threads, 8 elems each
  const float4* s = (const float4*)src + i * 2;
  float4 a = s[0], b = s[1];
  union { u16 h[8]; float4 f; } o;
  o.h[0] = f2bf(a.x); o.h[1] = f2bf(a.y); o.h[2] = f2bf(a.z); o.h[3] = f2bf(a.w);
  o.h[4] = f2bf(b.x); o.h[5] = f2bf(b.y); o.h[6] = f2bf(b.z); o.h[7] = f2bf(b.w);
  *(float4*)(dst + i * 8) = o.f;
}

struct W5 { const float* p[5]; };
__global__ __launch_bounds__(256) void conv_w_kernel(W5 w, u16* __restrict__ dst) {
  const int m = blockIdx.x >> 9;                                    // matrix idx
  const size_t i = (size_t)(blockIdx.x & 511) * 256 + threadIdx.x;  // 0..131071 (x8 elems)
  const float4* s = (const float4*)w.p[m] + i * 2;
  float4 a = s[0], b = s[1];
  union { u16 h[8]; float4 f; } o;
  o.h[0] = f2bf(a.x); o.h[1] = f2bf(a.y); o.h[2] = f2bf(a.z); o.h[3] = f2bf(a.w);
  o.h[4] = f2bf(b.x); o.h[5] = f2bf(b.y); o.h[6] = f2bf(b.z); o.h[7] = f2bf(b.w);
  *(float4*)(dst + ((size_t)m << 20) + i * 8) = o.f;
}

// ---- per-lane global address of a 16B chunk of the A operand ----
// ASRC 0: bf16 row-major [.][1024].  ASRC 1: bf16 Q-layout [N,H,S,DK].
template<int ASRC>
__device__ __forceinline__ const u16* aAddr(const u16* A, int row, int k) {
  if constexpr (ASRC == 0) {
    return A + (size_t)row * 1024 + k;
  } else {
    const int n = row >> 10, s = row & 1023, h = k >> 6;
    return A + ((size_t)((n * 16 + h) * 1024 + s)) * 64 + (k & 63);  // 16B chunk stays in one h
  }
}

// =====================================================================
// GEMM: C[m][col] = sum_k A[m][k] * W[col][k] + bias[col]
// m97 structure: linear LDS [128][32] bf16 tiles staged via
// global_load_lds width=16 (2 instr/wave/tile), 2 barriers per K-step,
// 8 ds_read_b128 + 16 MFMA per wave per K-step. A always bf16.
// WBF=1: W bf16 (global_load_lds). WBF=0: W f32 (reg-stage + convert).
// MODE 0: out bf16 Q-layout [N,H,S,DK]; MODE 1: out f32 [S,N,D];
// MODE 2: out bf16 V^T head layout [N,H,DK,S].
// =====================================================================
template<int MODE, int ASRC, int WBF>
__global__ __launch_bounds__(256, 2) void gemm_bt(const void* __restrict__ A,
                                                  const void* __restrict__ W,
                                                  const float* __restrict__ bias,
                                                  void* __restrict__ outv) {
  __shared__ __align__(16) u16 At[128 * 32];  // linear: row stride 64B (required by gld16)
  __shared__ __align__(16) u16 Bt[128 * 32];

  const int tid = threadIdx.x;
  const int lane = tid & 63, wave = tid >> 6;
  const int quad = lane >> 4, l16 = lane & 15;
  const int bm = blockIdx.y * 128, bn = blockIdx.x * 128;
  const int wm = (wave >> 1) * 64, wn = (wave & 1) * 64;

  // staging geometry: instr covers 16 rows; lane l -> row +(l>>2), k-chunk (l&3)*8
  const int r0 = wave * 32;            // wave's 32-row slice (2 instrs per tile)
  const int lrow = lane >> 2;          // 0..15
  const int lk = (lane & 3) * 8;       // 0,8,16,24 (bf16 elems)

  // W f32 fallback staging coords
  const int srow = tid >> 1, scol = (tid & 1) * 16;

  const u16* Ab = (const u16*)A;
  const u16* Wb = (const u16*)W;

  f32x4 acc[4][4];
#pragma unroll
  for (int i = 0; i < 4; i++)
#pragma unroll
    for (int j = 0; j < 4; j++) acc[i][j] = (f32x4){0.f, 0.f, 0.f, 0.f};

  for (int k0 = 0; k0 < 1024; k0 += 32) {
    float4 wf[4];
    if constexpr (!WBF) {  // issue f32 W loads early (regs only)
      const float* wp = (const float*)W + (size_t)(bn + srow) * 1024 + k0 + scol;
#pragma unroll
      for (int q = 0; q < 4; q++) wf[q] = ((const float4*)wp)[q];
    }
    __syncthreads();  // previous K-step's ds_reads complete; LDS reusable
    // ---- stage A tile (and W tile if bf16) via direct-to-LDS DMA ----
    gld16(aAddr<ASRC>(Ab, bm + r0 + lrow, k0 + lk), At + r0 * 32);
    gld16(aAddr<ASRC>(Ab, bm + r0 + 16 + lrow, k0 + lk), At + (r0 + 16) * 32);
    if constexpr (WBF) {
      gld16(Wb + (size_t)(bn + r0 + lrow) * 1024 + k0 + lk, Bt + r0 * 32);
      gld16(Wb + (size_t)(bn + r0 + 16 + lrow) * 1024 + k0 + lk, Bt + (r0 + 16) * 32);
    } else {
      Pack16 pb;
#pragma unroll
      for (int q = 0; q < 4; q++) {
        pb.h[q * 4 + 0] = f2bf(wf[q].x);
        pb.h[q * 4 + 1] = f2bf(wf[q].y);
        pb.h[q * 4 + 2] = f2bf(wf[q].z);
        pb.h[q * 4 + 3] = f2bf(wf[q].w);
      }
      *(float4*)(Bt + srow * 32 + scol) = pb.f4[0];
      *(float4*)(Bt + srow * 32 + scol + 8) = pb.f4[1];
    }
    __syncthreads();  // implicit vmcnt(0)+lgkmcnt(0): staged tiles visible

    // ---- fragments + MFMA ----
    bf16x8 af[4], bfr[4];
#pragma unroll
    for (int mt = 0; mt < 4; mt++)
      af[mt] = *(const bf16x8*)(At + (wm + mt * 16 + l16) * 32 + quad * 8);
#pragma unroll
    for (int nt = 0; nt < 4; nt++)
      bfr[nt] = *(const bf16x8*)(Bt + (wn + nt * 16 + l16) * 32 + quad * 8);
#pragma unroll
    for (int mt = 0; mt < 4; mt++)
#pragma unroll
      for (int nt = 0; nt < 4; nt++)
        acc[mt][nt] = __builtin_amdgcn_mfma_f32_16x16x32_bf16(af[mt], bfr[nt], acc[mt][nt], 0, 0, 0);
  }

#pragma unroll
  for (int mt = 0; mt < 4; mt++) {
#pragma unroll
    for (int nt = 0; nt < 4; nt++) {
      const int col = bn + wn + nt * 16 + l16;
      const float bv = bias[col];
#pragma unroll
      for (int i = 0; i < 4; i++) {
        const int row = bm + wm + mt * 16 + quad * 4 + i;
        const float v = acc[mt][nt][i] + bv;
        if constexpr (MODE == 0) {
          const int s = row >> 3, n = row & 7;
          const int h = col >> 6, dk = col & 63;
          ((u16*)outv)[(size_t)(((n * 16 + h) * 1024 + s) * 64 + dk)] = f2bf(v);
        } else if constexpr (MODE == 1) {
          const int n = row >> 10, s = row & 1023;
          ((float*)outv)[(size_t)((s * 8 + n) * 1024 + col)] = v;  // f32 output!
        } else {  // MODE 2: V^T head layout [N,H,DK,S]
          const int s = row >> 3, n = row & 7;
          const int h = col >> 6, dk = col & 63;
          ((u16*)outv)[(size_t)(((n * 16 + h) * 64 + dk) * 1024 + s)] = f2bf(v);
        }
      }
    }
  }
}

// =====================================================================
// Flash attention. QC holds Q in [N,H,S,DK] bf16; ctx written to OUT
// (same layout; OUT==QC is safe: each block loads its own Q rows to
// registers before any write). V comes TRANSPOSED ([N,H,DK,S]).
// Block: 256 thr = 4 waves, 64 queries (16/wave), key tiles of 64.
// grid: (16 qtiles, 128 nh)
// =====================================================================
__global__ __launch_bounds__(256, 2) void attn_kernel(const u16* __restrict__ QC,
                                                      const u16* __restrict__ K,
                                                      const u16* __restrict__ Vt_g,
                                                      const int* __restrict__ mask,
                                                      u16* __restrict__ OUT) {
  __shared__ __align__(16) u16 Ks[64 * 72];     // [key][dk], stride 72
  __shared__ __align__(16) u16 Vt[64 * 64];     // [dk][key], XOR-swizzled 8-key blocks
  __shared__ __align__(16) u16 Ps[4 * 16 * 72]; // per-wave P tile [16][72]
  __shared__ float mbias[64];

  const int tid = threadIdx.x;
  const int lane = tid & 63, wave = tid >> 6;
  const int quad = lane >> 4, l16 = lane & 15;
  const int qt = blockIdx.x, nh = blockIdx.y;
  const int n = nh >> 4;
  const size_t base = (size_t)nh << 16;  // nh * 1024*64

  const int q0 = qt * 64 + wave * 16;
  bf16x8 qf0, qf1;
  {
    const u16* qp = QC + base + (size_t)(q0 + l16) * 64 + quad * 8;
    qf0 = *(const bf16x8*)qp;
    qf1 = *(const bf16x8*)(qp + 32);
  }

  float m_i[4], l_i[4];
  f32x4 o[4];
#pragma unroll
  for (int i = 0; i < 4; i++) { m_i[i] = -1e30f; l_i[i] = 0.f; }
#pragma unroll
  for (int d = 0; d < 4; d++) o[d] = (f32x4){0.f, 0.f, 0.f, 0.f};

  const int sr = tid >> 2;           // K: key row | V^T: dk row
  const int sc = (tid & 3) * 16;     // K: dk offset | V^T: key offset
  const u16* kbase = K + base + (size_t)sr * 64 + sc;
  const u16* vbase = Vt_g + base + (size_t)sr * 1024 + sc;
  u16* vdst0 = Vt + sr * 64 + ((((sc >> 3) + 0) ^ (sr & 7)) << 3);
  u16* vdst1 = Vt + sr * 64 + ((((sc >> 3) + 1) ^ (sr & 7)) << 3);
  u16* pw = Ps + wave * (16 * 72);

  for (int kt = 0; kt < 16; kt++) {
    float4 kv0 = *(const float4*)(kbase + kt * 64 * 64);
    float4 kv1 = *(const float4*)(kbase + kt * 64 * 64 + 8);
    float4 vv0 = *(const float4*)(vbase + kt * 64);
    float4 vv1 = *(const float4*)(vbase + kt * 64 + 8);
    int mk = (tid < 64) ? mask[n * 1024 + kt * 64 + tid] : 0;
    __syncthreads();  // protect previous iteration's LDS reads
    *(float4*)(Ks + sr * 72 + sc) = kv0;
    *(float4*)(Ks + sr * 72 + sc + 8) = kv1;
    *(float4*)vdst0 = vv0;
    *(float4*)vdst1 = vv1;
    if (tid < 64) mbias[tid] = mk ? -1e30f : 0.0f;
    __syncthreads();

    // ---- S = Q K^T / 8 + mask ----
    f32x4 sfr[4];
#pragma unroll
    for (int nt = 0; nt < 4; nt++) {
      bf16x8 b0 = *(const bf16x8*)(Ks + (nt * 16 + l16) * 72 + quad * 8);
      bf16x8 b1 = *(const bf16x8*)(Ks + (nt * 16 + l16) * 72 + 32 + quad * 8);
      f32x4 a = (f32x4){0.f, 0.f, 0.f, 0.f};
      a = __builtin_amdgcn_mfma_f32_16x16x32_bf16(qf0, b0, a, 0, 0, 0);
      a = __builtin_amdgcn_mfma_f32_16x16x32_bf16(qf1, b1, a, 0, 0, 0);
      sfr[nt] = a;
    }
    float mb[4];
#pragma unroll
    for (int nt = 0; nt < 4; nt++) mb[nt] = mbias[nt * 16 + l16];
#pragma unroll
    for (int nt = 0; nt < 4; nt++)
#pragma unroll
      for (int i = 0; i < 4; i++)
        sfr[nt][i] = sfr[nt][i] * 0.125f + mb[nt];

    // ---- online softmax ----
    float alpha[4];
#pragma unroll
    for (int i = 0; i < 4; i++) {
      float m = fmaxf(fmaxf(sfr[0][i], sfr[1][i]), fmaxf(sfr[2][i], sfr[3][i]));
#pragma unroll
      for (int off = 1; off < 16; off <<= 1) m = fmaxf(m, __shfl_xor(m, off, 64));
      float mn = fmaxf(m_i[i], m);
      alpha[i] = __expf(m_i[i] - mn);
      m_i[i] = mn;
    }
    float rs[4] = {0.f, 0.f, 0.f, 0.f};
#pragma unroll
    for (int nt = 0; nt < 4; nt++) {
#pragma unroll
      for (int i = 0; i < 4; i++) {
        float p = __expf(sfr[nt][i] - m_i[i]);
        rs[i] += p;
        pw[(quad * 4 + i) * 72 + nt * 16 + l16] = f2bf(p);
      }
    }
#pragma unroll
    for (int i = 0; i < 4; i++) {
      float s = rs[i];
#pragma unroll
      for (int off = 1; off < 16; off <<= 1) s += __shfl_xor(s, off, 64);
      l_i[i] = l_i[i] * alpha[i] + s;
    }
#pragma unroll
    for (int d = 0; d < 4; d++)
#pragma unroll
      for (int i = 0; i < 4; i++) o[d][i] *= alpha[i];
    __syncthreads();  // P tile visible

    // ---- O += P @ V (single swizzled b128 per B-fragment) ----
#pragma unroll
    for (int ks = 0; ks < 2; ks++) {
      bf16x8 pa = *(const bf16x8*)(pw + l16 * 72 + ks * 32 + quad * 8);
#pragma unroll
      for (int d = 0; d < 4; d++) {
        bf16x8 vb = *(const bf16x8*)(Vt + (d * 16 + l16) * 64 +
                                     (((ks * 4 + quad) ^ (l16 & 7)) << 3));
        o[d] = __builtin_amdgcn_mfma_f32_16x16x32_bf16(pa, vb, o[d], 0, 0, 0);
      }
    }
  }

#pragma unroll
  for (int i = 0; i < 4; i++) {
    const float inv = 1.0f / l_i[i];
    const int q = q0 + quad * 4 + i;
    const size_t ob = base + (size_t)q * 64;
#pragma unroll
    for (int d = 0; d < 4; d++)
      OUT[ob + d * 16 + l16] = f2bf(o[d][i] * inv);
  }
}

// =====================================================================
extern "C" void kernel_launch(void* const* d_in, const int* in_sizes, int n_in,
                              void* d_out, int out_size, void* d_ws, size_t ws_size,
                              hipStream_t stream) {
  const float* Qpoi = (const float*)d_in[0];
  const float* Qsvi = (const float*)d_in[1];
  const float* Kin  = (const float*)d_in[2];
  const float* Vin  = (const float*)d_in[3];
  const int* mask   = (const int*)d_in[4];
  const float* wq_poi_w = (const float*)d_in[5];
  const float* wq_poi_b = (const float*)d_in[6];
  const float* wq_svi_w = (const float*)d_in[7];
  const float* wq_svi_b = (const float*)d_in[8];
  const float* wk_w = (const float*)d_in[9];
  const float* wk_b = (const float*)d_in[10];
  const float* wv_w = (const float*)d_in[11];
  const float* wv_b = (const float*)d_in[12];
  const float* fc_w = (const float*)d_in[13];
  const float* fc_b = (const float*)d_in[14];

  const size_t SZ = (size_t)8 * 16 * 1024 * 64;   // 8,388,608 elems per slab
  const size_t WBE = (size_t)5 << 20;             // 5 weight matrices, bf16 elems
  u16* W0 = (u16*)d_ws;        // Kh head-layout
  u16* W1 = W0 + SZ;           // Vh TRANSPOSED head-layout [N,H,DK,S]
  u16* W2 = W1 + SZ;           // (tier3) svi-ctx slab
  const bool haveWb = ws_size >= (2 * SZ + WBE) * sizeof(u16);   // 44.0 MB
  const bool haveW2 = ws_size >= (3 * SZ + WBE) * sizeof(u16);   // 60.8 MB
  u16* WbWs = haveW2 ? (W2 + SZ) : (W1 + SZ);  // bf16 weights in ws when haveWb

  float* Of = (float*)d_out;   // f32 [2][SZ]; poi = R0R1, svi = R2R3
  u16* R0 = (u16*)d_out;               // conv_a scratch (A operand, bf16)
  u16* R1 = R0 + SZ;                   // tier1: bf16 proj weights (8 MB)
  u16* R2 = R0 + 2 * SZ;               // Qh_svi / ctx_svi
  u16* R3 = R0 + 3 * SZ;               // Qh_poi / ctx_poi

  u16* Wp = haveWb ? WbWs : R1;        // proj weight slab (wk,wv,wqs,wqp[,fc])

  dim3 bb(256, 1, 1);
  dim3 gg(8, 64);     // gemm: 512 blocks
  dim3 ga(16, 128);   // attn
  dim3 gc(4096);      // conv_a

  // 1. weights -> bf16 (5 mats into ws, or 4 into R1 with f32 fc fallback)
  {
    W5 w5{{wk_w, wv_w, wq_svi_w, wq_poi_w, fc_w}};
    const int nm = haveWb ? 5 : 4;
    hipLaunchKernelGGL(conv_w_kernel, dim3(nm * 512), bb, 0, stream, w5, Wp);
  }
  const u16* Wk  = Wp + ((size_t)0 << 20);
  const u16* Wv  = Wp + ((size_t)1 << 20);
  const u16* Wqs = Wp + ((size_t)2 << 20);
  const u16* Wqp = Wp + ((size_t)3 << 20);

  // 2-5. A-conversions + projections (all bf16 W path)
  hipLaunchKernelGGL(conv_a_kernel, gc, bb, 0, stream, Kin, R0);
  hipLaunchKernelGGL((gemm_bt<0, 0, 1>), gg, bb, 0, stream, (const void*)R0, (const void*)Wk, wk_b, (void*)W0);
  hipLaunchKernelGGL(conv_a_kernel, gc, bb, 0, stream, Vin, R0);
  hipLaunchKernelGGL((gemm_bt<2, 0, 1>), gg, bb, 0, stream, (const void*)R0, (const void*)Wv, wv_b, (void*)W1);
  hipLaunchKernelGGL(conv_a_kernel, gc, bb, 0, stream, Qsvi, R0);
  hipLaunchKernelGGL((gemm_bt<0, 0, 1>), gg, bb, 0, stream, (const void*)R0, (const void*)Wqs, wq_svi_b, (void*)R2);
  hipLaunchKernelGGL(conv_a_kernel, gc, bb, 0, stream, Qpoi, R0);
  hipLaunchKernelGGL((gemm_bt<0, 0, 1>), gg, bb, 0, stream, (const void*)R0, (const void*)Wqp, wq_poi_b, (void*)R3);

  // 6-7. attention (svi ctx -> W2 when available, else in-place R2; poi in-place R3)
  u16* ctx_svi = haveW2 ? W2 : R2;
  hipLaunchKernelGGL(attn_kernel, ga, bb, 0, stream, (const u16*)R2, (const u16*)W0, (const u16*)W1, mask, ctx_svi);
  hipLaunchKernelGGL(attn_kernel, ga, bb, 0, stream, (const u16*)R3, (const u16*)W0, (const u16*)W1, mask, R3);

  // 8. fc(poi): A=R3, out f32 -> R0R1 (conv scratch + tier1 weights dead by now)
  if (haveWb) {
    const u16* Wfc = Wp + ((size_t)4 << 20);
    hipLaunchKernelGGL((gemm_bt<1, 1, 1>), gg, bb, 0, stream, (const void*)R3, (const void*)Wfc, fc_b, (void*)Of);
    // 9. fc(svi): A outside R2R3 required
    if (haveW2) {
      hipLaunchKernelGGL((gemm_bt<1, 1, 1>), gg, bb, 0, stream, (const void*)W2, (const void*)Wfc, fc_b, (void*)(Of + SZ));
    } else {
      hipMemcpyAsync(W0, R2, SZ * sizeof(u16), hipMemcpyDeviceToDevice, stream);
      hipLaunchKernelGGL((gemm_bt<1, 1, 1>), gg, bb, 0, stream, (const void*)W0, (const void*)Wfc, fc_b, (void*)(Of + SZ));
    }
  } else {
    hipLaunchKernelGGL((gemm_bt<1, 1, 0>), gg, bb, 0, stream, (const void*)R3, (const void*)fc_w, fc_b, (void*)Of);
    hipMemcpyAsync(W0, R2, SZ * sizeof(u16), hipMemcpyDeviceToDevice, stream);
    hipLaunchKernelGGL((gemm_bt<1, 1, 0>), gg, bb, 0, stream, (const void*)W0, (const void*)fc_w, fc_b, (void*)(Of + SZ));
  }
}

// Round 4
// 547.220 us; speedup vs baseline: 1.7968x; 1.1188x over previous
//
#include <hip/hip_runtime.h>

typedef unsigned short u16;
typedef unsigned int u32;
typedef short bf16x8 __attribute__((ext_vector_type(8)));
typedef float f32x4 __attribute__((ext_vector_type(4)));

// ---- bf16 helpers ----
__device__ __forceinline__ u16 f2bf(float f) {
  union { float f; u32 i; } v; v.f = f;
  u32 x = v.i;
  return (u16)((x + 0x7fffu + ((x >> 16) & 1u)) >> 16);  // RNE
}

union Pack16 { u16 h[16]; float4 f4[2]; };

// ---- direct global->LDS DMA, 16B per lane (wave-uniform LDS base) ----
__device__ __forceinline__ void gld16(const u16* g, u16* l) {
  __builtin_amdgcn_global_load_lds((const __attribute__((address_space(1))) u32*)g,
                                   (__attribute__((address_space(3))) u32*)l, 16, 0, 0);
}

// =====================================================================
// f32 -> bf16 streaming converters
// =====================================================================
__global__ __launch_bounds__(256) void conv_a_kernel(const float* __restrict__ src,
                                                     u16* __restrict__ dst) {
  const size_t i = (size_t)blockIdx.x * 256 + threadIdx.x;  // 1,048,576 threads, 8 elems each
  const float4* s = (const float4*)src + i * 2;
  float4 a = s[0], b = s[1];
  union { u16 h[8]; float4 f; } o;
  o.h[0] = f2bf(a.x); o.h[1] = f2bf(a.y); o.h[2] = f2bf(a.z); o.h[3] = f2bf(a.w);
  o.h[4] = f2bf(b.x); o.h[5] = f2bf(b.y); o.h[6] = f2bf(b.z); o.h[7] = f2bf(b.w);
  *(float4*)(dst + i * 8) = o.f;
}

struct W5 { const float* p[5]; };
__global__ __launch_bounds__(256) void conv_w_kernel(W5 w, u16* __restrict__ dst) {
  const int m = blockIdx.x >> 9;                                    // matrix idx
  const size_t i = (size_t)(blockIdx.x & 511) * 256 + threadIdx.x;  // 0..131071 (x8 elems)
  const float4* s = (const float4*)w.p[m] + i * 2;
  float4 a = s[0], b = s[1];
  union { u16 h[8]; float4 f; } o;
  o.h[0] = f2bf(a.x); o.h[1] = f2bf(a.y); o.h[2] = f2bf(a.z); o.h[3] = f2bf(a.w);
  o.h[4] = f2bf(b.x); o.h[5] = f2bf(b.y); o.h[6] = f2bf(b.z); o.h[7] = f2bf(b.w);
  *(float4*)(dst + ((size_t)m << 20) + i * 8) = o.f;
}

// ---- per-lane global address of a 16B chunk of the A operand ----
// ASRC 0: bf16 row-major [.][1024].  ASRC 1: bf16 Q-layout [N,H,S,DK].
template<int ASRC>
__device__ __forceinline__ const u16* aAddr(const u16* A, int row, int k) {
  if constexpr (ASRC == 0) {
    return A + (size_t)row * 1024 + k;
  } else {
    const int n = row >> 10, s = row & 1023, h = k >> 6;
    return A + ((size_t)((n * 16 + h) * 1024 + s)) * 64 + (k & 63);  // 16B chunk stays in one h
  }
}

// =====================================================================
// GEMM: C[m][col] = sum_k A[m][k] * W[col][k] + bias[col]
// m97 structure: linear LDS [128][32] bf16 tiles staged via
// global_load_lds width=16 (2 instr/wave/tile), 2 barriers per K-step,
// 8 ds_read_b128 + 16 MFMA per wave per K-step. A always bf16.
// WBF=1: W bf16 (global_load_lds). WBF=0: W f32 (reg-stage + convert).
// MODE 0: out bf16 Q-layout [N,H,S,DK]; MODE 1: out f32 [S,N,D];
// MODE 2: out bf16 V^T head layout [N,H,DK,S].
// =====================================================================
template<int MODE, int ASRC, int WBF>
__global__ __launch_bounds__(256, 2) void gemm_bt(const void* __restrict__ A,
                                                  const void* __restrict__ W,
                                                  const float* __restrict__ bias,
                                                  void* __restrict__ outv) {
  __shared__ __align__(16) u16 At[128 * 32];  // linear: row stride 64B (required by gld16)
  __shared__ __align__(16) u16 Bt[128 * 32];

  const int tid = threadIdx.x;
  const int lane = tid & 63, wave = tid >> 6;
  const int quad = lane >> 4, l16 = lane & 15;
  const int bm = blockIdx.y * 128, bn = blockIdx.x * 128;
  const int wm = (wave >> 1) * 64, wn = (wave & 1) * 64;

  const int r0 = wave * 32;            // wave's 32-row slice (2 instrs per tile)
  const int lrow = lane >> 2;          // 0..15
  const int lk = (lane & 3) * 8;       // 0,8,16,24 (bf16 elems)

  const int srow = tid >> 1, scol = (tid & 1) * 16;  // W f32 fallback coords

  const u16* Ab = (const u16*)A;
  const u16* Wb = (const u16*)W;

  f32x4 acc[4][4];
#pragma unroll
  for (int i = 0; i < 4; i++)
#pragma unroll
    for (int j = 0; j < 4; j++) acc[i][j] = (f32x4){0.f, 0.f, 0.f, 0.f};

  for (int k0 = 0; k0 < 1024; k0 += 32) {
    float4 wf[4];
    if constexpr (!WBF) {
      const float* wp = (const float*)W + (size_t)(bn + srow) * 1024 + k0 + scol;
#pragma unroll
      for (int q = 0; q < 4; q++) wf[q] = ((const float4*)wp)[q];
    }
    __syncthreads();  // previous K-step's ds_reads complete; LDS reusable
    gld16(aAddr<ASRC>(Ab, bm + r0 + lrow, k0 + lk), At + r0 * 32);
    gld16(aAddr<ASRC>(Ab, bm + r0 + 16 + lrow, k0 + lk), At + (r0 + 16) * 32);
    if constexpr (WBF) {
      gld16(Wb + (size_t)(bn + r0 + lrow) * 1024 + k0 + lk, Bt + r0 * 32);
      gld16(Wb + (size_t)(bn + r0 + 16 + lrow) * 1024 + k0 + lk, Bt + (r0 + 16) * 32);
    } else {
      Pack16 pb;
#pragma unroll
      for (int q = 0; q < 4; q++) {
        pb.h[q * 4 + 0] = f2bf(wf[q].x);
        pb.h[q * 4 + 1] = f2bf(wf[q].y);
        pb.h[q * 4 + 2] = f2bf(wf[q].z);
        pb.h[q * 4 + 3] = f2bf(wf[q].w);
      }
      *(float4*)(Bt + srow * 32 + scol) = pb.f4[0];
      *(float4*)(Bt + srow * 32 + scol + 8) = pb.f4[1];
    }
    __syncthreads();  // staged tiles visible

    bf16x8 af[4], bfr[4];
#pragma unroll
    for (int mt = 0; mt < 4; mt++)
      af[mt] = *(const bf16x8*)(At + (wm + mt * 16 + l16) * 32 + quad * 8);
#pragma unroll
    for (int nt = 0; nt < 4; nt++)
      bfr[nt] = *(const bf16x8*)(Bt + (wn + nt * 16 + l16) * 32 + quad * 8);
#pragma unroll
    for (int mt = 0; mt < 4; mt++)
#pragma unroll
      for (int nt = 0; nt < 4; nt++)
        acc[mt][nt] = __builtin_amdgcn_mfma_f32_16x16x32_bf16(af[mt], bfr[nt], acc[mt][nt], 0, 0, 0);
  }

#pragma unroll
  for (int mt = 0; mt < 4; mt++) {
#pragma unroll
    for (int nt = 0; nt < 4; nt++) {
      const int col = bn + wn + nt * 16 + l16;
      const float bv = bias[col];
#pragma unroll
      for (int i = 0; i < 4; i++) {
        const int row = bm + wm + mt * 16 + quad * 4 + i;
        const float v = acc[mt][nt][i] + bv;
        if constexpr (MODE == 0) {
          const int s = row >> 3, n = row & 7;
          const int h = col >> 6, dk = col & 63;
          ((u16*)outv)[(size_t)(((n * 16 + h) * 1024 + s) * 64 + dk)] = f2bf(v);
        } else if constexpr (MODE == 1) {
          const int n = row >> 10, s = row & 1023;
          ((float*)outv)[(size_t)((s * 8 + n) * 1024 + col)] = v;  // f32 output!
        } else {  // MODE 2: V^T head layout [N,H,DK,S]
          const int s = row >> 3, n = row & 7;
          const int h = col >> 6, dk = col & 63;
          ((u16*)outv)[(size_t)(((n * 16 + h) * 64 + dk) * 1024 + s)] = f2bf(v);
        }
      }
    }
  }
}

// =====================================================================
// FUSED dual-stream flash attention: both Q streams (svi, poi) against
// the SAME K/V. K-fragments and V-fragments are read from LDS once and
// feed both streams' MFMAs; staging/barriers amortized 2x; the two
// dependency chains interleave (MFMA pipe || VALU softmax).
// Row-sum l_i comes from an extra MFMA with a constant ones-column
// B-fragment (col 0 = row-sums of P), rescaled by alpha like O, and
// broadcast from the l16==0 lane at the end. In-place OUT==Q safe.
// Block: 256 thr = 4 waves, 64 queries/stream (16/wave), key tiles 64.
// grid: (16 qtiles, 128 nh)
// =====================================================================
__global__ __launch_bounds__(256, 2) void attn2_kernel(const u16* __restrict__ Qs_g,
                                                       const u16* __restrict__ Qp_g,
                                                       const u16* __restrict__ K,
                                                       const u16* __restrict__ Vt_g,
                                                       const int* __restrict__ mask,
                                                       u16* __restrict__ OUTs,
                                                       u16* __restrict__ OUTp) {
  __shared__ __align__(16) u16 Ks[64 * 72];      // [key][dk], stride 72
  __shared__ __align__(16) u16 Vt[64 * 64];      // [dk][key], XOR-swizzled 8-key blocks
  __shared__ __align__(16) u16 PsS[4 * 16 * 72]; // per-wave P tile, svi
  __shared__ __align__(16) u16 PsP[4 * 16 * 72]; // per-wave P tile, poi
  __shared__ float mbias[64];

  const int tid = threadIdx.x;
  const int lane = tid & 63, wave = tid >> 6;
  const int quad = lane >> 4, l16 = lane & 15;
  const int qt = blockIdx.x, nh = blockIdx.y;
  const int n = nh >> 4;
  const size_t base = (size_t)nh << 16;  // nh * 1024*64

  const int q0 = qt * 64 + wave * 16;
  bf16x8 qS0, qS1, qP0, qP1;
  {
    const u16* qp = Qs_g + base + (size_t)(q0 + l16) * 64 + quad * 8;
    qS0 = *(const bf16x8*)qp;
    qS1 = *(const bf16x8*)(qp + 32);
    const u16* qq = Qp_g + base + (size_t)(q0 + l16) * 64 + quad * 8;
    qP0 = *(const bf16x8*)qq;
    qP1 = *(const bf16x8*)(qq + 32);
  }

  float mS[4], mP[4];
  f32x4 oS[4], oP[4], lS, lP;
#pragma unroll
  for (int i = 0; i < 4; i++) { mS[i] = -1e30f; mP[i] = -1e30f; }
#pragma unroll
  for (int d = 0; d < 4; d++) { oS[d] = (f32x4){0.f, 0.f, 0.f, 0.f}; oP[d] = (f32x4){0.f, 0.f, 0.f, 0.f}; }
  lS = (f32x4){0.f, 0.f, 0.f, 0.f};
  lP = (f32x4){0.f, 0.f, 0.f, 0.f};

  // constant B-fragment: column 0 = all ones -> D[:,0] = row-sums of A
  bf16x8 vbOnes;
  {
    const short ob = (l16 == 0) ? (short)0x3F80 : (short)0;
#pragma unroll
    for (int j = 0; j < 8; j++) vbOnes[j] = ob;
  }

  const int sr = tid >> 2;           // K: key row | V^T: dk row
  const int sc = (tid & 3) * 16;     // K: dk offset | V^T: key offset
  const u16* kbase = K + base + (size_t)sr * 64 + sc;
  const u16* vbase = Vt_g + base + (size_t)sr * 1024 + sc;
  u16* vdst0 = Vt + sr * 64 + ((((sc >> 3) + 0) ^ (sr & 7)) << 3);
  u16* vdst1 = Vt + sr * 64 + ((((sc >> 3) + 1) ^ (sr & 7)) << 3);
  u16* pwS = PsS + wave * (16 * 72);
  u16* pwP = PsP + wave * (16 * 72);

  for (int kt = 0; kt < 16; kt++) {
    // ---- stage K tile + V^T tile (swizzled) + mask bias ----
    float4 kv0 = *(const float4*)(kbase + kt * 64 * 64);
    float4 kv1 = *(const float4*)(kbase + kt * 64 * 64 + 8);
    float4 vv0 = *(const float4*)(vbase + kt * 64);
    float4 vv1 = *(const float4*)(vbase + kt * 64 + 8);
    int mk = (tid < 64) ? mask[n * 1024 + kt * 64 + tid] : 0;
    __syncthreads();  // previous iteration's LDS reads complete
    *(float4*)(Ks + sr * 72 + sc) = kv0;
    *(float4*)(Ks + sr * 72 + sc + 8) = kv1;
    *(float4*)vdst0 = vv0;
    *(float4*)vdst1 = vv1;
    if (tid < 64) mbias[tid] = mk ? -1e30f : 0.0f;
    __syncthreads();

    // ---- S = Q K^T / 8 + mask, both streams (K fragments read ONCE) ----
    f32x4 sS[4], sP[4];
#pragma unroll
    for (int nt = 0; nt < 4; nt++) {
      bf16x8 b0 = *(const bf16x8*)(Ks + (nt * 16 + l16) * 72 + quad * 8);
      bf16x8 b1 = *(const bf16x8*)(Ks + (nt * 16 + l16) * 72 + 32 + quad * 8);
      f32x4 a = (f32x4){0.f, 0.f, 0.f, 0.f};
      a = __builtin_amdgcn_mfma_f32_16x16x32_bf16(qS0, b0, a, 0, 0, 0);
      a = __builtin_amdgcn_mfma_f32_16x16x32_bf16(qS1, b1, a, 0, 0, 0);
      sS[nt] = a;
      f32x4 c = (f32x4){0.f, 0.f, 0.f, 0.f};
      c = __builtin_amdgcn_mfma_f32_16x16x32_bf16(qP0, b0, c, 0, 0, 0);
      c = __builtin_amdgcn_mfma_f32_16x16x32_bf16(qP1, b1, c, 0, 0, 0);
      sP[nt] = c;
    }
    float mb[4];
#pragma unroll
    for (int nt = 0; nt < 4; nt++) mb[nt] = mbias[nt * 16 + l16];
#pragma unroll
    for (int nt = 0; nt < 4; nt++)
#pragma unroll
      for (int i = 0; i < 4; i++) {
        sS[nt][i] = sS[nt][i] * 0.125f + mb[nt];
        sP[nt][i] = sP[nt][i] * 0.125f + mb[nt];
      }

    // ---- online softmax (both streams); l handled by MFMA later ----
#pragma unroll
    for (int i = 0; i < 4; i++) {
      float m = fmaxf(fmaxf(sS[0][i], sS[1][i]), fmaxf(sS[2][i], sS[3][i]));
#pragma unroll
      for (int off = 1; off < 16; off <<= 1) m = fmaxf(m, __shfl_xor(m, off, 64));
      float mn = fmaxf(mS[i], m);
      float alpha = __expf(mS[i] - mn);
      mS[i] = mn;
#pragma unroll
      for (int d = 0; d < 4; d++) oS[d][i] *= alpha;
      lS[i] *= alpha;
    }
#pragma unroll
    for (int i = 0; i < 4; i++) {
      float m = fmaxf(fmaxf(sP[0][i], sP[1][i]), fmaxf(sP[2][i], sP[3][i]));
#pragma unroll
      for (int off = 1; off < 16; off <<= 1) m = fmaxf(m, __shfl_xor(m, off, 64));
      float mn = fmaxf(mP[i], m);
      float alpha = __expf(mP[i] - mn);
      mP[i] = mn;
#pragma unroll
      for (int d = 0; d < 4; d++) oP[d][i] *= alpha;
      lP[i] *= alpha;
    }
#pragma unroll
    for (int nt = 0; nt < 4; nt++)
#pragma unroll
      for (int i = 0; i < 4; i++) {
        pwS[(quad * 4 + i) * 72 + nt * 16 + l16] = f2bf(__expf(sS[nt][i] - mS[i]));
        pwP[(quad * 4 + i) * 72 + nt * 16 + l16] = f2bf(__expf(sP[nt][i] - mP[i]));
      }
    __syncthreads();  // P tiles visible

    // ---- O += P @ V, l += P @ ones (V fragments read ONCE) ----
#pragma unroll
    for (int ks = 0; ks < 2; ks++) {
      bf16x8 paS = *(const bf16x8*)(pwS + l16 * 72 + ks * 32 + quad * 8);
      bf16x8 paP = *(const bf16x8*)(pwP + l16 * 72 + ks * 32 + quad * 8);
      lS = __builtin_amdgcn_mfma_f32_16x16x32_bf16(paS, vbOnes, lS, 0, 0, 0);
      lP = __builtin_amdgcn_mfma_f32_16x16x32_bf16(paP, vbOnes, lP, 0, 0, 0);
#pragma unroll
      for (int d = 0; d < 4; d++) {
        bf16x8 vb = *(const bf16x8*)(Vt + (d * 16 + l16) * 64 +
                                     (((ks * 4 + quad) ^ (l16 & 7)) << 3));
        oS[d] = __builtin_amdgcn_mfma_f32_16x16x32_bf16(paS, vb, oS[d], 0, 0, 0);
        oP[d] = __builtin_amdgcn_mfma_f32_16x16x32_bf16(paP, vb, oP[d], 0, 0, 0);
      }
    }
  }

  // ---- epilogue: l lives in lane l16==0 of each quad group; broadcast ----
#pragma unroll
  for (int i = 0; i < 4; i++) {
    const float lsv = __shfl(lS[i], lane & 48, 64);
    const float lpv = __shfl(lP[i], lane & 48, 64);
    const float invS = 1.0f / lsv;
    const float invP = 1.0f / lpv;
    const int q = q0 + quad * 4 + i;
    const size_t ob = base + (size_t)q * 64;
#pragma unroll
    for (int d = 0; d < 4; d++) {
      OUTs[ob + d * 16 + l16] = f2bf(oS[d][i] * invS);
      OUTp[ob + d * 16 + l16] = f2bf(oP[d][i] * invP);
    }
  }
}

// =====================================================================
extern "C" void kernel_launch(void* const* d_in, const int* in_sizes, int n_in,
                              void* d_out, int out_size, void* d_ws, size_t ws_size,
                              hipStream_t stream) {
  const float* Qpoi = (const float*)d_in[0];
  const float* Qsvi = (const float*)d_in[1];
  const float* Kin  = (const float*)d_in[2];
  const float* Vin  = (const float*)d_in[3];
  const int* mask   = (const int*)d_in[4];
  const float* wq_poi_w = (const float*)d_in[5];
  const float* wq_poi_b = (const float*)d_in[6];
  const float* wq_svi_w = (const float*)d_in[7];
  const float* wq_svi_b = (const float*)d_in[8];
  const float* wk_w = (const float*)d_in[9];
  const float* wk_b = (const float*)d_in[10];
  const float* wv_w = (const float*)d_in[11];
  const float* wv_b = (const float*)d_in[12];
  const float* fc_w = (const float*)d_in[13];
  const float* fc_b = (const float*)d_in[14];

  const size_t SZ = (size_t)8 * 16 * 1024 * 64;   // 8,388,608 elems per slab
  const size_t WBE = (size_t)5 << 20;             // 5 weight matrices, bf16 elems
  u16* W0 = (u16*)d_ws;        // Kh head-layout
  u16* W1 = W0 + SZ;           // Vh TRANSPOSED head-layout [N,H,DK,S]
  u16* W2 = W1 + SZ;           // (tier3) svi-ctx slab
  const bool haveWb = ws_size >= (2 * SZ + WBE) * sizeof(u16);   // 44.0 MB
  const bool haveW2 = ws_size >= (3 * SZ + WBE) * sizeof(u16);   // 60.8 MB
  u16* WbWs = haveW2 ? (W2 + SZ) : (W1 + SZ);

  float* Of = (float*)d_out;   // f32 [2][SZ]; poi = R0R1, svi = R2R3
  u16* R0 = (u16*)d_out;               // conv_a scratch (A operand, bf16)
  u16* R1 = R0 + SZ;                   // tier1: bf16 proj weights (8 MB)
  u16* R2 = R0 + 2 * SZ;               // Qh_svi / ctx_svi
  u16* R3 = R0 + 3 * SZ;               // Qh_poi / ctx_poi

  u16* Wp = haveWb ? WbWs : R1;        // proj weight slab (wk,wv,wqs,wqp[,fc])

  dim3 bb(256, 1, 1);
  dim3 gg(8, 64);     // gemm: 512 blocks
  dim3 ga(16, 128);   // attn
  dim3 gc(4096);      // conv_a

  // 1. weights -> bf16 (5 mats into ws, or 4 into R1 with f32 fc fallback)
  {
    W5 w5{{wk_w, wv_w, wq_svi_w, wq_poi_w, fc_w}};
    const int nm = haveWb ? 5 : 4;
    hipLaunchKernelGGL(conv_w_kernel, dim3(nm * 512), bb, 0, stream, w5, Wp);
  }
  const u16* Wk  = Wp + ((size_t)0 << 20);
  const u16* Wv  = Wp + ((size_t)1 << 20);
  const u16* Wqs = Wp + ((size_t)2 << 20);
  const u16* Wqp = Wp + ((size_t)3 << 20);

  // 2-5. A-conversions + projections
  hipLaunchKernelGGL(conv_a_kernel, gc, bb, 0, stream, Kin, R0);
  hipLaunchKernelGGL((gemm_bt<0, 0, 1>), gg, bb, 0, stream, (const void*)R0, (const void*)Wk, wk_b, (void*)W0);
  hipLaunchKernelGGL(conv_a_kernel, gc, bb, 0, stream, Vin, R0);
  hipLaunchKernelGGL((gemm_bt<2, 0, 1>), gg, bb, 0, stream, (const void*)R0, (const void*)Wv, wv_b, (void*)W1);
  hipLaunchKernelGGL(conv_a_kernel, gc, bb, 0, stream, Qsvi, R0);
  hipLaunchKernelGGL((gemm_bt<0, 0, 1>), gg, bb, 0, stream, (const void*)R0, (const void*)Wqs, wq_svi_b, (void*)R2);
  hipLaunchKernelGGL(conv_a_kernel, gc, bb, 0, stream, Qpoi, R0);
  hipLaunchKernelGGL((gemm_bt<0, 0, 1>), gg, bb, 0, stream, (const void*)R0, (const void*)Wqp, wq_poi_b, (void*)R3);

  // 6. FUSED attention: both streams, one pass over K/V
  u16* ctx_svi = haveW2 ? W2 : R2;
  hipLaunchKernelGGL(attn2_kernel, ga, bb, 0, stream,
                     (const u16*)R2, (const u16*)R3, (const u16*)W0, (const u16*)W1,
                     mask, ctx_svi, R3);

  // 7. fc(poi): A=R3 -> f32 Of lower half (R0R1 region; conv scratch dead)
  if (haveWb) {
    const u16* Wfc = Wp + ((size_t)4 << 20);
    hipLaunchKernelGGL((gemm_bt<1, 1, 1>), gg, bb, 0, stream, (const void*)R3, (const void*)Wfc, fc_b, (void*)Of);
    if (haveW2) {
      hipLaunchKernelGGL((gemm_bt<1, 1, 1>), gg, bb, 0, stream, (const void*)W2, (const void*)Wfc, fc_b, (void*)(Of + SZ));
    } else {
      hipMemcpyAsync(W0, R2, SZ * sizeof(u16), hipMemcpyDeviceToDevice, stream);
      hipLaunchKernelGGL((gemm_bt<1, 1, 1>), gg, bb, 0, stream, (const void*)W0, (const void*)Wfc, fc_b, (void*)(Of + SZ));
    }
  } else {
    hipLaunchKernelGGL((gemm_bt<1, 1, 0>), gg, bb, 0, stream, (const void*)R3, (const void*)fc_w, fc_b, (void*)Of);
    hipMemcpyAsync(W0, R2, SZ * sizeof(u16), hipMemcpyDeviceToDevice, stream);
    hipLaunchKernelGGL((gemm_bt<1, 1, 0>), gg, bb, 0, stream, (const void*)W0, (const void*)fc_w, fc_b, (void*)(Of + SZ));
  }
}

// Round 5
// 534.592 us; speedup vs baseline: 1.8393x; 1.0236x over previous
//
#include <hip/hip_runtime.h>

typedef unsigned short u16;
typedef unsigned int u32;
typedef short bf16x8 __attribute__((ext_vector_type(8)));
typedef float f32x4 __attribute__((ext_vector_type(4)));

// ---- bf16 helpers ----
__device__ __forceinline__ u16 f2bf(float f) {
  union { float f; u32 i; } v; v.f = f;
  u32 x = v.i;
  return (u16)((x + 0x7fffu + ((x >> 16) & 1u)) >> 16);  // RNE
}

union Pack16 { u16 h[16]; float4 f4[2]; };

// ---- direct global->LDS DMA, 16B per lane (wave-uniform LDS base) ----
__device__ __forceinline__ void gld16(const u16* g, u16* l) {
  __builtin_amdgcn_global_load_lds((const __attribute__((address_space(1))) u32*)g,
                                   (__attribute__((address_space(3))) u32*)l, 16, 0, 0);
}

// =====================================================================
// f32 -> bf16 streaming converters (z-batched pair + 5-weight batch)
// =====================================================================
struct C2 { const float* s[2]; u16* d[2]; };
__global__ __launch_bounds__(256) void conv2_kernel(C2 c) {
  const int z = blockIdx.z;
  const size_t i = (size_t)blockIdx.x * 256 + threadIdx.x;  // x8 elems
  const float4* s = (const float4*)c.s[z] + i * 2;
  float4 a = s[0], b = s[1];
  union { u16 h[8]; float4 f; } o;
  o.h[0] = f2bf(a.x); o.h[1] = f2bf(a.y); o.h[2] = f2bf(a.z); o.h[3] = f2bf(a.w);
  o.h[4] = f2bf(b.x); o.h[5] = f2bf(b.y); o.h[6] = f2bf(b.z); o.h[7] = f2bf(b.w);
  *(float4*)(c.d[z] + i * 8) = o.f;
}

struct W5 { const float* p[5]; };
__global__ __launch_bounds__(256) void conv_w_kernel(W5 w, u16* __restrict__ dst) {
  const int m = blockIdx.x >> 9;                                    // matrix idx
  const size_t i = (size_t)(blockIdx.x & 511) * 256 + threadIdx.x;  // x8 elems
  const float4* s = (const float4*)w.p[m] + i * 2;
  float4 a = s[0], b = s[1];
  union { u16 h[8]; float4 f; } o;
  o.h[0] = f2bf(a.x); o.h[1] = f2bf(a.y); o.h[2] = f2bf(a.z); o.h[3] = f2bf(a.w);
  o.h[4] = f2bf(b.x); o.h[5] = f2bf(b.y); o.h[6] = f2bf(b.z); o.h[7] = f2bf(b.w);
  *(float4*)(dst + ((size_t)m << 20) + i * 8) = o.f;
}

// ---- per-lane global address of a 16B chunk of the A operand ----
// ASRC 0: bf16 row-major [.][1024].  ASRC 1: bf16 Q-layout [N,H,S,DK].
template<int ASRC>
__device__ __forceinline__ const u16* aAddr(const u16* A, int row, int k) {
  if constexpr (ASRC == 0) {
    return A + (size_t)row * 1024 + k;
  } else {
    const int n = row >> 10, s = row & 1023, h = k >> 6;
    return A + ((size_t)((n * 16 + h) * 1024 + s)) * 64 + (k & 63);  // 16B chunk stays in one h
  }
}

// =====================================================================
// z-BATCHED GEMM: two independent GEMMs per launch (blockIdx.z selects
// pointers) -> 1024 blocks = 4 blocks/CU (m97's proven occupancy regime;
// the 2-barrier K-loop needs >=3 resident blocks to hide the staging
// drain via wave overlap, m114). Inner loop identical to round 3.
// MODE 0: out bf16 Q-layout; MODE 1: out f32 [S,N,D]; MODE 2: V^T layout.
// =====================================================================
struct GB { const void* A[2]; const void* W[2]; const float* bias[2]; void* out[2]; };

template<int MODEA, int MODEB, int ASRC, int WBF>
__global__ __launch_bounds__(256, 2) void gemm_bt(GB gb) {
  __shared__ __align__(16) u16 At[128 * 32];  // linear: row stride 64B (required by gld16)
  __shared__ __align__(16) u16 Bt[128 * 32];

  const int z = blockIdx.z;
  const u16* Ab = (const u16*)gb.A[z];
  const u16* Wb = (const u16*)gb.W[z];
  const float* bias = gb.bias[z];
  void* outv = gb.out[z];
  const int mode = z ? MODEB : MODEA;

  const int tid = threadIdx.x;
  const int lane = tid & 63, wave = tid >> 6;
  const int quad = lane >> 4, l16 = lane & 15;
  const int bm = blockIdx.y * 128, bn = blockIdx.x * 128;
  const int wm = (wave >> 1) * 64, wn = (wave & 1) * 64;

  const int r0 = wave * 32;            // wave's 32-row slice (2 instrs per tile)
  const int lrow = lane >> 2;          // 0..15
  const int lk = (lane & 3) * 8;       // 0,8,16,24 (bf16 elems)

  const int srow = tid >> 1, scol = (tid & 1) * 16;  // W f32 fallback coords

  f32x4 acc[4][4];
#pragma unroll
  for (int i = 0; i < 4; i++)
#pragma unroll
    for (int j = 0; j < 4; j++) acc[i][j] = (f32x4){0.f, 0.f, 0.f, 0.f};

  for (int k0 = 0; k0 < 1024; k0 += 32) {
    float4 wf[4];
    if constexpr (!WBF) {
      const float* wp = (const float*)Wb + (size_t)(bn + srow) * 1024 + k0 + scol;
#pragma unroll
      for (int q = 0; q < 4; q++) wf[q] = ((const float4*)wp)[q];
    }
    __syncthreads();  // previous K-step's ds_reads complete; LDS reusable
    gld16(aAddr<ASRC>(Ab, bm + r0 + lrow, k0 + lk), At + r0 * 32);
    gld16(aAddr<ASRC>(Ab, bm + r0 + 16 + lrow, k0 + lk), At + (r0 + 16) * 32);
    if constexpr (WBF) {
      gld16(Wb + (size_t)(bn + r0 + lrow) * 1024 + k0 + lk, Bt + r0 * 32);
      gld16(Wb + (size_t)(bn + r0 + 16 + lrow) * 1024 + k0 + lk, Bt + (r0 + 16) * 32);
    } else {
      Pack16 pb;
#pragma unroll
      for (int q = 0; q < 4; q++) {
        pb.h[q * 4 + 0] = f2bf(wf[q].x);
        pb.h[q * 4 + 1] = f2bf(wf[q].y);
        pb.h[q * 4 + 2] = f2bf(wf[q].z);
        pb.h[q * 4 + 3] = f2bf(wf[q].w);
      }
      *(float4*)(Bt + srow * 32 + scol) = pb.f4[0];
      *(float4*)(Bt + srow * 32 + scol + 8) = pb.f4[1];
    }
    __syncthreads();  // staged tiles visible

    bf16x8 af[4], bfr[4];
#pragma unroll
    for (int mt = 0; mt < 4; mt++)
      af[mt] = *(const bf16x8*)(At + (wm + mt * 16 + l16) * 32 + quad * 8);
#pragma unroll
    for (int nt = 0; nt < 4; nt++)
      bfr[nt] = *(const bf16x8*)(Bt + (wn + nt * 16 + l16) * 32 + quad * 8);
#pragma unroll
    for (int mt = 0; mt < 4; mt++)
#pragma unroll
      for (int nt = 0; nt < 4; nt++)
        acc[mt][nt] = __builtin_amdgcn_mfma_f32_16x16x32_bf16(af[mt], bfr[nt], acc[mt][nt], 0, 0, 0);
  }

#pragma unroll
  for (int mt = 0; mt < 4; mt++) {
#pragma unroll
    for (int nt = 0; nt < 4; nt++) {
      const int col = bn + wn + nt * 16 + l16;
      const float bv = bias[col];
#pragma unroll
      for (int i = 0; i < 4; i++) {
        const int row = bm + wm + mt * 16 + quad * 4 + i;
        const float v = acc[mt][nt][i] + bv;
        if (mode == 0) {
          const int s = row >> 3, n = row & 7;
          const int h = col >> 6, dk = col & 63;
          ((u16*)outv)[(size_t)(((n * 16 + h) * 1024 + s) * 64 + dk)] = f2bf(v);
        } else if (mode == 1) {
          const int n = row >> 10, s = row & 1023;
          ((float*)outv)[(size_t)((s * 8 + n) * 1024 + col)] = v;  // f32 output!
        } else {  // MODE 2: V^T head layout [N,H,DK,S]
          const int s = row >> 3, n = row & 7;
          const int h = col >> 6, dk = col & 63;
          ((u16*)outv)[(size_t)(((n * 16 + h) * 64 + dk) * 1024 + s)] = f2bf(v);
        }
      }
    }
  }
}

// =====================================================================
// FUSED dual-stream flash attention (unchanged from round 4).
// =====================================================================
__global__ __launch_bounds__(256, 2) void attn2_kernel(const u16* __restrict__ Qs_g,
                                                       const u16* __restrict__ Qp_g,
                                                       const u16* __restrict__ K,
                                                       const u16* __restrict__ Vt_g,
                                                       const int* __restrict__ mask,
                                                       u16* __restrict__ OUTs,
                                                       u16* __restrict__ OUTp) {
  __shared__ __align__(16) u16 Ks[64 * 72];      // [key][dk], stride 72
  __shared__ __align__(16) u16 Vt[64 * 64];      // [dk][key], XOR-swizzled 8-key blocks
  __shared__ __align__(16) u16 PsS[4 * 16 * 72]; // per-wave P tile, svi
  __shared__ __align__(16) u16 PsP[4 * 16 * 72]; // per-wave P tile, poi
  __shared__ float mbias[64];

  const int tid = threadIdx.x;
  const int lane = tid & 63, wave = tid >> 6;
  const int quad = lane >> 4, l16 = lane & 15;
  const int qt = blockIdx.x, nh = blockIdx.y;
  const int n = nh >> 4;
  const size_t base = (size_t)nh << 16;  // nh * 1024*64

  const int q0 = qt * 64 + wave * 16;
  bf16x8 qS0, qS1, qP0, qP1;
  {
    const u16* qp = Qs_g + base + (size_t)(q0 + l16) * 64 + quad * 8;
    qS0 = *(const bf16x8*)qp;
    qS1 = *(const bf16x8*)(qp + 32);
    const u16* qq = Qp_g + base + (size_t)(q0 + l16) * 64 + quad * 8;
    qP0 = *(const bf16x8*)qq;
    qP1 = *(const bf16x8*)(qq + 32);
  }

  float mS[4], mP[4];
  f32x4 oS[4], oP[4], lS, lP;
#pragma unroll
  for (int i = 0; i < 4; i++) { mS[i] = -1e30f; mP[i] = -1e30f; }
#pragma unroll
  for (int d = 0; d < 4; d++) { oS[d] = (f32x4){0.f, 0.f, 0.f, 0.f}; oP[d] = (f32x4){0.f, 0.f, 0.f, 0.f}; }
  lS = (f32x4){0.f, 0.f, 0.f, 0.f};
  lP = (f32x4){0.f, 0.f, 0.f, 0.f};

  // constant B-fragment: column 0 = all ones -> D[:,0] = row-sums of A
  bf16x8 vbOnes;
  {
    const short ob = (l16 == 0) ? (short)0x3F80 : (short)0;
#pragma unroll
    for (int j = 0; j < 8; j++) vbOnes[j] = ob;
  }

  const int sr = tid >> 2;           // K: key row | V^T: dk row
  const int sc = (tid & 3) * 16;     // K: dk offset | V^T: key offset
  const u16* kbase = K + base + (size_t)sr * 64 + sc;
  const u16* vbase = Vt_g + base + (size_t)sr * 1024 + sc;
  u16* vdst0 = Vt + sr * 64 + ((((sc >> 3) + 0) ^ (sr & 7)) << 3);
  u16* vdst1 = Vt + sr * 64 + ((((sc >> 3) + 1) ^ (sr & 7)) << 3);
  u16* pwS = PsS + wave * (16 * 72);
  u16* pwP = PsP + wave * (16 * 72);

  for (int kt = 0; kt < 16; kt++) {
    // ---- stage K tile + V^T tile (swizzled) + mask bias ----
    float4 kv0 = *(const float4*)(kbase + kt * 64 * 64);
    float4 kv1 = *(const float4*)(kbase + kt * 64 * 64 + 8);
    float4 vv0 = *(const float4*)(vbase + kt * 64);
    float4 vv1 = *(const float4*)(vbase + kt * 64 + 8);
    int mk = (tid < 64) ? mask[n * 1024 + kt * 64 + tid] : 0;
    __syncthreads();  // previous iteration's LDS reads complete
    *(float4*)(Ks + sr * 72 + sc) = kv0;
    *(float4*)(Ks + sr * 72 + sc + 8) = kv1;
    *(float4*)vdst0 = vv0;
    *(float4*)vdst1 = vv1;
    if (tid < 64) mbias[tid] = mk ? -1e30f : 0.0f;
    __syncthreads();

    // ---- S = Q K^T / 8 + mask, both streams (K fragments read ONCE) ----
    f32x4 sS[4], sP[4];
#pragma unroll
    for (int nt = 0; nt < 4; nt++) {
      bf16x8 b0 = *(const bf16x8*)(Ks + (nt * 16 + l16) * 72 + quad * 8);
      bf16x8 b1 = *(const bf16x8*)(Ks + (nt * 16 + l16) * 72 + 32 + quad * 8);
      f32x4 a = (f32x4){0.f, 0.f, 0.f, 0.f};
      a = __builtin_amdgcn_mfma_f32_16x16x32_bf16(qS0, b0, a, 0, 0, 0);
      a = __builtin_amdgcn_mfma_f32_16x16x32_bf16(qS1, b1, a, 0, 0, 0);
      sS[nt] = a;
      f32x4 c = (f32x4){0.f, 0.f, 0.f, 0.f};
      c = __builtin_amdgcn_mfma_f32_16x16x32_bf16(qP0, b0, c, 0, 0, 0);
      c = __builtin_amdgcn_mfma_f32_16x16x32_bf16(qP1, b1, c, 0, 0, 0);
      sP[nt] = c;
    }
    float mb[4];
#pragma unroll
    for (int nt = 0; nt < 4; nt++) mb[nt] = mbias[nt * 16 + l16];
#pragma unroll
    for (int nt = 0; nt < 4; nt++)
#pragma unroll
      for (int i = 0; i < 4; i++) {
        sS[nt][i] = sS[nt][i] * 0.125f + mb[nt];
        sP[nt][i] = sP[nt][i] * 0.125f + mb[nt];
      }

    // ---- online softmax (both streams) ----
#pragma unroll
    for (int i = 0; i < 4; i++) {
      float m = fmaxf(fmaxf(sS[0][i], sS[1][i]), fmaxf(sS[2][i], sS[3][i]));
#pragma unroll
      for (int off = 1; off < 16; off <<= 1) m = fmaxf(m, __shfl_xor(m, off, 64));
      float mn = fmaxf(mS[i], m);
      float alpha = __expf(mS[i] - mn);
      mS[i] = mn;
#pragma unroll
      for (int d = 0; d < 4; d++) oS[d][i] *= alpha;
      lS[i] *= alpha;
    }
#pragma unroll
    for (int i = 0; i < 4; i++) {
      float m = fmaxf(fmaxf(sP[0][i], sP[1][i]), fmaxf(sP[2][i], sP[3][i]));
#pragma unroll
      for (int off = 1; off < 16; off <<= 1) m = fmaxf(m, __shfl_xor(m, off, 64));
      float mn = fmaxf(mP[i], m);
      float alpha = __expf(mP[i] - mn);
      mP[i] = mn;
#pragma unroll
      for (int d = 0; d < 4; d++) oP[d][i] *= alpha;
      lP[i] *= alpha;
    }
#pragma unroll
    for (int nt = 0; nt < 4; nt++)
#pragma unroll
      for (int i = 0; i < 4; i++) {
        pwS[(quad * 4 + i) * 72 + nt * 16 + l16] = f2bf(__expf(sS[nt][i] - mS[i]));
        pwP[(quad * 4 + i) * 72 + nt * 16 + l16] = f2bf(__expf(sP[nt][i] - mP[i]));
      }
    __syncthreads();  // P tiles visible

    // ---- O += P @ V, l += P @ ones (V fragments read ONCE) ----
#pragma unroll
    for (int ks = 0; ks < 2; ks++) {
      bf16x8 paS = *(const bf16x8*)(pwS + l16 * 72 + ks * 32 + quad * 8);
      bf16x8 paP = *(const bf16x8*)(pwP + l16 * 72 + ks * 32 + quad * 8);
      lS = __builtin_amdgcn_mfma_f32_16x16x32_bf16(paS, vbOnes, lS, 0, 0, 0);
      lP = __builtin_amdgcn_mfma_f32_16x16x32_bf16(paP, vbOnes, lP, 0, 0, 0);
#pragma unroll
      for (int d = 0; d < 4; d++) {
        bf16x8 vb = *(const bf16x8*)(Vt + (d * 16 + l16) * 64 +
                                     (((ks * 4 + quad) ^ (l16 & 7)) << 3));
        oS[d] = __builtin_amdgcn_mfma_f32_16x16x32_bf16(paS, vb, oS[d], 0, 0, 0);
        oP[d] = __builtin_amdgcn_mfma_f32_16x16x32_bf16(paP, vb, oP[d], 0, 0, 0);
      }
    }
  }

  // ---- epilogue: l lives in lane l16==0 of each quad group; broadcast ----
#pragma unroll
  for (int i = 0; i < 4; i++) {
    const float lsv = __shfl(lS[i], lane & 48, 64);
    const float lpv = __shfl(lP[i], lane & 48, 64);
    const float invS = 1.0f / lsv;
    const float invP = 1.0f / lpv;
    const int q = q0 + quad * 4 + i;
    const size_t ob = base + (size_t)q * 64;
#pragma unroll
    for (int d = 0; d < 4; d++) {
      OUTs[ob + d * 16 + l16] = f2bf(oS[d][i] * invS);
      OUTp[ob + d * 16 + l16] = f2bf(oP[d][i] * invP);
    }
  }
}

// =====================================================================
extern "C" void kernel_launch(void* const* d_in, const int* in_sizes, int n_in,
                              void* d_out, int out_size, void* d_ws, size_t ws_size,
                              hipStream_t stream) {
  const float* Qpoi = (const float*)d_in[0];
  const float* Qsvi = (const float*)d_in[1];
  const float* Kin  = (const float*)d_in[2];
  const float* Vin  = (const float*)d_in[3];
  const int* mask   = (const int*)d_in[4];
  const float* wq_poi_w = (const float*)d_in[5];
  const float* wq_poi_b = (const float*)d_in[6];
  const float* wq_svi_w = (const float*)d_in[7];
  const float* wq_svi_b = (const float*)d_in[8];
  const float* wk_w = (const float*)d_in[9];
  const float* wk_b = (const float*)d_in[10];
  const float* wv_w = (const float*)d_in[11];
  const float* wv_b = (const float*)d_in[12];
  const float* fc_w = (const float*)d_in[13];
  const float* fc_b = (const float*)d_in[14];

  const size_t SZ = (size_t)8 * 16 * 1024 * 64;   // 8,388,608 elems per slab
  const size_t WBE = (size_t)5 << 20;             // 5 weight matrices, bf16 elems
  u16* W0 = (u16*)d_ws;        // Kh head-layout -> later poi-ctx bounce
  u16* W1 = W0 + SZ;           // Vh TRANSPOSED head-layout -> later svi-ctx bounce
  u16* Wp = W1 + SZ;           // bf16 weights (5 x 1M elems) when ws fits
  const bool haveWb = ws_size >= (2 * SZ + WBE) * sizeof(u16);   // 44.0 MB

  float* Of = (float*)d_out;   // f32 [2][SZ]; poi half 0, svi half 1
  u16* R0 = (u16*)d_out;       // bf16 A slab 0
  u16* R1 = R0 + SZ;           // bf16 A slab 1
  u16* R2 = R0 + 2 * SZ;       // Qh_svi / ctx_svi
  u16* R3 = R0 + 3 * SZ;       // Qh_poi / ctx_poi

  dim3 bb(256, 1, 1);
  dim3 gg(8, 64, 2);   // batched gemm: 1024 blocks = 4 blocks/CU
  dim3 ga(16, 128);    // attn
  dim3 gc(4096, 1, 2); // batched conv pair

  // 1. weights -> bf16 (all 5 into ws); tier fallback: f32 weights in-GEMM
  if (haveWb) {
    W5 w5{{wk_w, wv_w, wq_svi_w, wq_poi_w, fc_w}};
    hipLaunchKernelGGL(conv_w_kernel, dim3(2560), bb, 0, stream, w5, Wp);
  }
  const u16* Wk  = Wp + ((size_t)0 << 20);
  const u16* Wv  = Wp + ((size_t)1 << 20);
  const u16* Wqs = Wp + ((size_t)2 << 20);
  const u16* Wqp = Wp + ((size_t)3 << 20);
  const u16* Wfc = Wp + ((size_t)4 << 20);

  // 2. phase A: K,V -> bf16; batched {K-proj->W0 (MODE0), V-proj->W1 (MODE2)}
  {
    C2 c{{Kin, Vin}, {R0, R1}};
    hipLaunchKernelGGL(conv2_kernel, gc, bb, 0, stream, c);
    GB g{{R0, R1},
         {haveWb ? (const void*)Wk : (const void*)wk_w, haveWb ? (const void*)Wv : (const void*)wv_w},
         {wk_b, wv_b}, {(void*)W0, (void*)W1}};
    if (haveWb) hipLaunchKernelGGL((gemm_bt<0, 2, 0, 1>), gg, bb, 0, stream, g);
    else        hipLaunchKernelGGL((gemm_bt<0, 2, 0, 0>), gg, bb, 0, stream, g);
  }

  // 3. phase B: Qsvi,Qpoi -> bf16; batched {svi-proj->R2, poi-proj->R3}
  {
    C2 c{{Qsvi, Qpoi}, {R0, R1}};
    hipLaunchKernelGGL(conv2_kernel, gc, bb, 0, stream, c);
    GB g{{R0, R1},
         {haveWb ? (const void*)Wqs : (const void*)wq_svi_w, haveWb ? (const void*)Wqp : (const void*)wq_poi_w},
         {wq_svi_b, wq_poi_b}, {(void*)R2, (void*)R3}};
    if (haveWb) hipLaunchKernelGGL((gemm_bt<0, 0, 0, 1>), gg, bb, 0, stream, g);
    else        hipLaunchKernelGGL((gemm_bt<0, 0, 0, 0>), gg, bb, 0, stream, g);
  }

  // 4. fused attention, ctx in-place (own-Q-rows trick)
  hipLaunchKernelGGL(attn2_kernel, ga, bb, 0, stream,
                     (const u16*)R2, (const u16*)R3, (const u16*)W0, (const u16*)W1,
                     mask, R2, R3);

  // 5. bounce ctx out of d_out (Kh/Vt dead after attn); then batched fc
  hipMemcpyAsync(W0, R3, SZ * sizeof(u16), hipMemcpyDeviceToDevice, stream);  // poi ctx
  hipMemcpyAsync(W1, R2, SZ * sizeof(u16), hipMemcpyDeviceToDevice, stream);  // svi ctx
  {
    GB g{{W0, W1},
         {haveWb ? (const void*)Wfc : (const void*)fc_w, haveWb ? (const void*)Wfc : (const void*)fc_w},
         {fc_b, fc_b}, {(void*)Of, (void*)(Of + SZ)}};
    if (haveWb) hipLaunchKernelGGL((gemm_bt<1, 1, 1, 1>), gg, bb, 0, stream, g);
    else        hipLaunchKernelGGL((gemm_bt<1, 1, 1, 0>), gg, bb, 0, stream, g);
  }
}